// Round 5
// baseline (329.597 us; speedup 1.0000x reference)
//
#include <hip/hip_runtime.h>
#include <math.h>

// ---------------- workspace layout (float offsets) ----------------
// All weights pre-transposed so the hot kernel reads row-contiguous float4.
#define OFF_W2PT 0             // [192][64]  (Wm2 . P), folded s1=v1+v4, TRANSPOSED [o][c]
#define OFF_B2P  12288         // [192]
#define OFF_WM1T 12480         // [64][128]  Wm1T[c][m]
#define OFF_W0T  20672         // [32][128]  W0T[u][m]
#define OFF_W1T  24768         // [32][64]   W1T[u][m]
#define OFF_W2T  26816         // [32][32]   W2T[u][m]
#define WS_FLOATS 27840

#define SC_Y0 0.0180421959121758f   // (1/sqrt(32))*(1/sqrt(96))
#define SC_Y2 0.015625f             // (1/sqrt(32))*(1/sqrt(128))
#define S2f 0.70710678118654752f
#define S6f 0.40824829046386302f
#define TWOS2f 1.41421356237309505f
#define TWOS6f 0.81649658092772603f
#define ISQRT3 0.57735026918962576f
#define ISQRT5 0.44721359549995794f
#define H0SC 0.08838834764831845f   // 1/sqrt(128)
#define H1SC 0.125f                 // 1/sqrt(64)
#define H2SC 0.17677669529663689f   // 1/sqrt(32)

__device__ static inline float dot32(const float* __restrict__ a,
                                     const float* __restrict__ b) {
  const float4* a4 = (const float4*)a;
  const float4* b4 = (const float4*)b;
  float acc = 0.f;
#pragma unroll
  for (int q = 0; q < 8; ++q) {
    float4 x = a4[q], y = b4[q];
    acc += x.x * y.x + x.y * y.y + x.z * y.z + x.w * y.w;
  }
  return acc;
}

// ---------------- prep: W2PT (folded), B2P, weight transposes, zero out ----------------
// 6 folded columns: s'0=k0*P0[0:32]*Y0, s'1=(k1*P2[0:32]+k5*P2[64:96])*Y2,
// s'2=k2*P0[32:64]*Y0, s'3=k4*P2[32:64]*Y2, s'4=k6*P0[64:96]*Y0, s'5=k8*P2[96:128]*Y2
__global__ __launch_bounds__(256) void prep_kernel(
    const float* __restrict__ Wm2, const float* __restrict__ bm2,
    const float* __restrict__ P0, const float* __restrict__ P2,
    const float* __restrict__ Wm1, const float* __restrict__ W0e,
    const float* __restrict__ W1o, const float* __restrict__ W2e,
    float* __restrict__ ws, float* __restrict__ out) {
  int j = blockIdx.x * 256 + threadIdx.x;
  if (j < 2304) out[j] = 0.f;

  if (j < 12288) {
    // W2PT[o][c] at ws[j], o=j>>6, c=j&63
    const int o = j >> 6, c = j & 63;
    const int s = o >> 5, u = o & 31;
    int k; const float* P; float sc;
    switch (s) {
      case 0: k = 0; P = P0;      sc = SC_Y0; break;
      case 1: k = 1; P = P2;      sc = SC_Y2; break;
      case 2: k = 2; P = P0 + 32; sc = SC_Y0; break;
      case 3: k = 4; P = P2 + 32; sc = SC_Y2; break;
      case 4: k = 6; P = P0 + 64; sc = SC_Y0; break;
      default: k = 8; P = P2 + 96; sc = SC_Y2; break;
    }
    float acc = dot32(Wm2 + c * 9216 + k * 1024 + u * 32, P);
    if (s == 1) acc += dot32(Wm2 + c * 9216 + 5 * 1024 + u * 32, P2 + 64);
    ws[OFF_W2PT + j] = acc * sc;
  } else if (j < 12480) {
    const int o = j - 12288;
    const int s = o >> 5, u = o & 31;
    int k; const float* P; float sc;
    switch (s) {
      case 0: k = 0; P = P0;      sc = SC_Y0; break;
      case 1: k = 1; P = P2;      sc = SC_Y2; break;
      case 2: k = 2; P = P0 + 32; sc = SC_Y0; break;
      case 3: k = 4; P = P2 + 32; sc = SC_Y2; break;
      case 4: k = 6; P = P0 + 64; sc = SC_Y0; break;
      default: k = 8; P = P2 + 96; sc = SC_Y2; break;
    }
    float acc = dot32(bm2 + k * 1024 + u * 32, P);
    if (s == 1) acc += dot32(bm2 + 5 * 1024 + u * 32, P2 + 64);
    ws[OFF_B2P + o] = acc * sc;
  } else if (j < 20672) {
    const int idx = j - 12480;  // Wm1T[c][m] = Wm1[m*64+c]
    const int c = idx >> 7, m = idx & 127;
    ws[j] = Wm1[m * 64 + c];
  } else if (j < 24768) {
    const int idx = j - 20672;  // W0T[u][m] = W0e[m*32+u]
    const int u = idx >> 7, m = idx & 127;
    ws[j] = W0e[m * 32 + u];
  } else if (j < 26816) {
    const int idx = j - 24768;  // W1T[u][m] = W1o[m*32+u]
    const int u = idx >> 6, m = idx & 63;
    ws[j] = W1o[m * 32 + u];
  } else if (j < 27840) {
    const int idx = j - 26816;  // W2T[u][m] = W2e[m*32+u]
    const int u = idx >> 5, m = idx & 31;
    ws[j] = W2e[m * 32 + u];
  }
}

// ---------------- fused: MLP + V + projections + path math + reduce, 8-node tile ----------------
// LDS 9408 B: Vt[8][192] + hiT[64][12] + sphs[8][6]  -> 8 blocks/CU possible at <=64 VGPR.
// No staging: x reads are broadcast float4 from global (round-4 evidence: FETCH 24->27MB only).
// Register discipline (round-2/4 lesson): max ~26 live floats in any phase; keep bound (256,6)
// which empirically yields no-spill allocation on this body shape (round 3: VGPR 40).
__global__ __launch_bounds__(256, 6) void fused_kernel(
    const float* __restrict__ xs_g, const float* __restrict__ xsph,
    const float* __restrict__ bm1, const float* __restrict__ ws,
    const int* __restrict__ batch, float* __restrict__ out, const float norm2) {
  __shared__ __align__(16) float Vt[8][192];
  __shared__ __align__(16) float hiT[64][12];
  __shared__ float sphs[8][6];

  const int tid = threadIdx.x;
  const int n0 = blockIdx.x * 8;

  // ---- phase 2: hidden = silu(x_scalar @ Wm1 + bm1): 8n x 64c; thread = (n=tid>>5, 2c) ----
  {
    const int n = tid >> 5, c0 = (tid & 31) * 2;
    const float* xr = xs_g + (size_t)(n0 + n) * 128;
    const float* w0r = ws + OFF_WM1T + c0 * 128;
    const float* w1r = w0r + 128;
    float acc0 = 0.f, acc1 = 0.f;
#pragma unroll 4
    for (int mq = 0; mq < 32; ++mq) {
      const float4 xv = *(const float4*)(xr + mq * 4);
      const float4 wa = *(const float4*)(w0r + mq * 4);
      const float4 wb = *(const float4*)(w1r + mq * 4);
      acc0 += xv.x * wa.x + xv.y * wa.y + xv.z * wa.z + xv.w * wa.w;
      acc1 += xv.x * wb.x + xv.y * wb.y + xv.z * wb.z + xv.w * wb.w;
    }
    const float z0 = acc0 + bm1[c0];
    const float z1 = acc1 + bm1[c0 + 1];
    hiT[c0][n] = z0 / (1.f + __expf(-z0));
    hiT[c0 + 1][n] = z1 / (1.f + __expf(-z1));
  }
  __syncthreads();  // hiT ready

  // ---- phase 3: V[n][o] = b2p[o] + sum_c hi[n][c]*W2PT[o][c]; all 256 threads ----
  // thread = (ob=tid&63 -> cols ob, ob+64, ob+128; np=tid>>6 -> nodes 2np, 2np+1)
  {
    const int ob = tid & 63, np = tid >> 6;
    const int na = np * 2;
    float acc00, acc01, acc10, acc11, acc20, acc21;
    {
      const float b0 = ws[OFF_B2P + ob];
      const float b1 = ws[OFF_B2P + ob + 64];
      const float b2 = ws[OFF_B2P + ob + 128];
      acc00 = b0; acc01 = b0; acc10 = b1; acc11 = b1; acc20 = b2; acc21 = b2;
    }
    const float* w0 = ws + OFF_W2PT + ob * 64;
    const float* w1 = ws + OFF_W2PT + (ob + 64) * 64;
    const float* w2 = ws + OFF_W2PT + (ob + 128) * 64;
#pragma unroll 4
    for (int c4 = 0; c4 < 16; ++c4) {
      const float4 wA = *(const float4*)(w0 + c4 * 4);
      const float4 wB = *(const float4*)(w1 + c4 * 4);
      const float4 wC = *(const float4*)(w2 + c4 * 4);
      {
        const float2 h = *(const float2*)&hiT[c4 * 4 + 0][na];
        acc00 += h.x * wA.x; acc01 += h.y * wA.x;
        acc10 += h.x * wB.x; acc11 += h.y * wB.x;
        acc20 += h.x * wC.x; acc21 += h.y * wC.x;
      }
      {
        const float2 h = *(const float2*)&hiT[c4 * 4 + 1][na];
        acc00 += h.x * wA.y; acc01 += h.y * wA.y;
        acc10 += h.x * wB.y; acc11 += h.y * wB.y;
        acc20 += h.x * wC.y; acc21 += h.y * wC.y;
      }
      {
        const float2 h = *(const float2*)&hiT[c4 * 4 + 2][na];
        acc00 += h.x * wA.z; acc01 += h.y * wA.z;
        acc10 += h.x * wB.z; acc11 += h.y * wB.z;
        acc20 += h.x * wC.z; acc21 += h.y * wC.z;
      }
      {
        const float2 h = *(const float2*)&hiT[c4 * 4 + 3][na];
        acc00 += h.x * wA.w; acc01 += h.y * wA.w;
        acc10 += h.x * wB.w; acc11 += h.y * wB.w;
        acc20 += h.x * wC.w; acc21 += h.y * wC.w;
      }
    }
    Vt[na][ob]           = acc00;  Vt[na + 1][ob]           = acc01;
    Vt[na][ob + 64]      = acc10;  Vt[na + 1][ob + 64]      = acc11;
    Vt[na][ob + 128]     = acc20;  Vt[na + 1][ob + 128]     = acc21;
  }

  // ---- phase B: h0/h1/h2 from global x_sph (broadcast float4) + transposed weights ----
  const int u = tid & 31, ni = tid >> 5;
  const float* row = xsph + (size_t)(n0 + ni) * 480;

  float h0;
  {
    const float* wr = ws + OFF_W0T + u * 128;
    float a0 = 0.f;
#pragma unroll 4
    for (int mq = 0; mq < 32; ++mq) {
      const float4 xv = *(const float4*)(row + mq * 4);
      const float4 wv = *(const float4*)(wr + mq * 4);
      a0 += xv.x * wv.x + xv.y * wv.y + xv.z * wv.z + xv.w * wv.w;
    }
    h0 = a0 * H0SC;
  }

  float h1a, h1b, h1c;
  {
    const float* wr = ws + OFF_W1T + u * 64;
    float a10 = 0.f, a11 = 0.f, a12 = 0.f;
#pragma unroll 2
    for (int mq = 0; mq < 16; ++mq) {  // 4 m-values per iter
      const float4 wv = *(const float4*)(wr + mq * 4);
      const float4 b0 = *(const float4*)(row + 128 + mq * 12);
      const float4 b1 = *(const float4*)(row + 128 + mq * 12 + 4);
      const float4 b2 = *(const float4*)(row + 128 + mq * 12 + 8);
      a10 += b0.x * wv.x; a11 += b0.y * wv.x; a12 += b0.z * wv.x;
      a10 += b0.w * wv.y; a11 += b1.x * wv.y; a12 += b1.y * wv.y;
      a10 += b1.z * wv.z; a11 += b1.w * wv.z; a12 += b2.x * wv.z;
      a10 += b2.y * wv.w; a11 += b2.z * wv.w; a12 += b2.w * wv.w;
    }
    h1a = a10 * H1SC; h1b = a11 * H1SC; h1c = a12 * H1SC;
  }

  float h2v[5];
  {
    const float* wr = ws + OFF_W2T + u * 32;
    float a20 = 0.f, a21 = 0.f, a22 = 0.f, a23 = 0.f, a24 = 0.f;
#pragma unroll 2
    for (int mq = 0; mq < 8; ++mq) {  // 4 m-values per iter
      const float4 wv = *(const float4*)(wr + mq * 4);
      const float4 c0v = *(const float4*)(row + 320 + mq * 20);
      const float4 c1v = *(const float4*)(row + 320 + mq * 20 + 4);
      const float4 c2v = *(const float4*)(row + 320 + mq * 20 + 8);
      const float4 c3v = *(const float4*)(row + 320 + mq * 20 + 12);
      const float4 c4v = *(const float4*)(row + 320 + mq * 20 + 16);
      a20 += c0v.x * wv.x; a21 += c0v.y * wv.x; a22 += c0v.z * wv.x; a23 += c0v.w * wv.x; a24 += c1v.x * wv.x;
      a20 += c1v.y * wv.y; a21 += c1v.z * wv.y; a22 += c1v.w * wv.y; a23 += c2v.x * wv.y; a24 += c2v.y * wv.y;
      a20 += c2v.z * wv.z; a21 += c2v.w * wv.z; a22 += c3v.x * wv.z; a23 += c3v.y * wv.z; a24 += c3v.z * wv.z;
      a20 += c3v.w * wv.w; a21 += c4v.x * wv.w; a22 += c4v.y * wv.w; a23 += c4v.z * wv.w; a24 += c4v.w * wv.w;
    }
    h2v[0] = a20 * H2SC; h2v[1] = a21 * H2SC; h2v[2] = a22 * H2SC;
    h2v[3] = a23 * H2SC; h2v[4] = a24 * H2SC;
  }
  __syncthreads();  // Vt ready

  // ---- phase D: path math + u-reduction (verbatim KD math; folded V columns) ----
  {
    const float* Vp = &Vt[ni][u];
    const float v0 = Vp[0], v15 = Vp[32], v2 = Vp[64], v3 = Vp[96];
    const float v5 = Vp[128], v6 = Vp[160];

    const float d11 = h1a * h1a + h1b * h1b + h1c * h1c;
    const float d22 = h2v[0] * h2v[0] + h2v[1] * h2v[1] + h2v[2] * h2v[2] +
                      h2v[3] * h2v[3] + h2v[4] * h2v[4];
    float y0 = v0 * h0 * h0 + v2 * d11 * ISQRT3 + v5 * d22 * ISQRT5;

    const float o00 = h1a * h1a, o01 = h1a * h1b, o02 = h1a * h1c;
    const float o11 = h1b * h1b, o12 = h1b * h1c, o22 = h1c * h1c;
    const float t40 = TWOS2f * o01, t41 = TWOS2f * o12;
    const float t42 = S6f * (2.f * o22 - o00 - o11);
    const float t43 = TWOS2f * o02, t44 = S2f * (o00 - o11);

    const float A00 = -S6f * h2v[2] + S2f * h2v[4];
    const float A01 = S2f * h2v[0];
    const float A02 = S2f * h2v[3];
    const float A11 = -S6f * h2v[2] - S2f * h2v[4];
    const float A12 = S2f * h2v[1];
    const float A22 = TWOS6f * h2v[2];
    const float B00 = A00 * A00 + A01 * A01 + A02 * A02;
    const float B01 = A00 * A01 + A01 * A11 + A02 * A12;
    const float B02 = A00 * A02 + A01 * A12 + A02 * A22;
    const float B11 = A01 * A01 + A11 * A11 + A12 * A12;
    const float B12 = A01 * A02 + A11 * A12 + A12 * A22;
    const float B22 = A02 * A02 + A12 * A12 + A22 * A22;
    const float t80 = TWOS2f * B01, t81 = TWOS2f * B12;
    const float t82 = S6f * (2.f * B22 - B00 - B11);
    const float t83 = TWOS2f * B02, t84 = S2f * (B00 - B11);

    const float w15 = v15 * h0;
    const float v6n = v6 * norm2;
    float y2r[5];
    y2r[0] = w15 * h2v[0] + v3 * t40 + v6n * t80;
    y2r[1] = w15 * h2v[1] + v3 * t41 + v6n * t81;
    y2r[2] = w15 * h2v[2] + v3 * t42 + v6n * t82;
    y2r[3] = w15 * h2v[3] + v3 * t43 + v6n * t83;
    y2r[4] = w15 * h2v[4] + v3 * t44 + v6n * t84;

#pragma unroll
    for (int off = 16; off > 0; off >>= 1) {
      y0 += __shfl_xor(y0, off, 32);
#pragma unroll
      for (int r = 0; r < 5; ++r) y2r[r] += __shfl_xor(y2r[r], off, 32);
    }

    if (u == 0) {
      sphs[ni][0] = y0;
#pragma unroll
      for (int r = 0; r < 5; ++r) sphs[ni][1 + r] = y2r[r];
    }
  }
  __syncthreads();

  // ---- phase E: Q-contract + segment atomics over the 8-node tile ----
  if (tid < 9) {
    const float QW[9][6] = {
        {ISQRT3, 0.f, 0.f, -S6f, 0.f, S2f},
        {0.f, S2f, 0.f, 0.f, 0.f, 0.f},
        {0.f, 0.f, 0.f, 0.f, S2f, 0.f},
        {0.f, S2f, 0.f, 0.f, 0.f, 0.f},
        {ISQRT3, 0.f, 0.f, -S6f, 0.f, -S2f},
        {0.f, 0.f, S2f, 0.f, 0.f, 0.f},
        {0.f, 0.f, 0.f, 0.f, S2f, 0.f},
        {0.f, 0.f, S2f, 0.f, 0.f, 0.f},
        {ISQRT3, 0.f, 0.f, TWOS6f, 0.f, 0.f}};
    const int a = tid / 3, b = tid % 3;
    const int rolled = ((a + 1) % 3) * 3 + ((b + 1) % 3);
    const float c0 = QW[tid][0], c1 = QW[tid][1], c2 = QW[tid][2];
    const float c3 = QW[tid][3], c4 = QW[tid][4], c5 = QW[tid][5];
    int cur_g = batch[n0];
    float acc = 0.f;
#pragma unroll
    for (int q = 0; q < 8; ++q) {
      const int g = batch[n0 + q];
      const float val = c0 * sphs[q][0] + c1 * sphs[q][1] + c2 * sphs[q][2] +
                        c3 * sphs[q][3] + c4 * sphs[q][4] + c5 * sphs[q][5];
      if (g != cur_g) {
        atomicAdd(out + cur_g * 9 + rolled, acc);
        acc = 0.f;
        cur_g = g;
      }
      acc += val;
    }
    atomicAdd(out + cur_g * 9 + rolled, acc);
  }
}

extern "C" void kernel_launch(void* const* d_in, const int* in_sizes, int n_in,
                              void* d_out, int out_size, void* d_ws, size_t ws_size,
                              hipStream_t stream) {
  const float* x_scalar = (const float*)d_in[0];
  const float* x_sph    = (const float*)d_in[1];
  const int*   batch    = (const int*)d_in[2];
  const float* W0e      = (const float*)d_in[3];
  const float* W1o      = (const float*)d_in[4];
  const float* W2e      = (const float*)d_in[5];
  const float* Wm1      = (const float*)d_in[6];
  const float* bm1      = (const float*)d_in[7];
  const float* Wm2      = (const float*)d_in[8];
  const float* bm2      = (const float*)d_in[9];
  const float* P0       = (const float*)d_in[10];
  // P1 (d_in[11]) provably unused: C111/C221 antisymmetric vs h(x)h of same h.
  const float* P2       = (const float*)d_in[12];
  float* ws  = (float*)d_ws;
  float* out = (float*)d_out;

  if (ws_size < (size_t)WS_FLOATS * sizeof(float)) return;

  // host-side C222 normalization (pure CPU double math; = sqrt(12/7))
  double Q2[5][3][3] = {};
  const double s2d = 0.70710678118654752440, s6d = 0.40824829046386301637;
  Q2[0][0][1] = Q2[0][1][0] = s2d;
  Q2[1][1][2] = Q2[1][2][1] = s2d;
  Q2[2][0][0] = Q2[2][1][1] = -s6d; Q2[2][2][2] = 2.0 * s6d;
  Q2[3][0][2] = Q2[3][2][0] = s2d;
  Q2[4][0][0] = s2d; Q2[4][1][1] = -s2d;
  double ss = 0.0;
  for (int i = 0; i < 5; ++i)
    for (int jj = 0; jj < 5; ++jj) {
      double S[3][3];
      for (int a = 0; a < 3; ++a)
        for (int d = 0; d < 3; ++d) {
          double m1 = 0, m2 = 0;
          for (int b = 0; b < 3; ++b) {
            m1 += Q2[i][a][b] * Q2[jj][d][b];
            m2 += Q2[i][d][b] * Q2[jj][a][b];
          }
          S[a][d] = 0.5 * (m1 + m2);
        }
      double tr = (S[0][0] + S[1][1] + S[2][2]) / 3.0;
      S[0][0] -= tr; S[1][1] -= tr; S[2][2] -= tr;
      for (int kk = 0; kk < 5; ++kk) {
        double cc = 0;
        for (int a = 0; a < 3; ++a)
          for (int d = 0; d < 3; ++d) cc += Q2[kk][a][d] * S[a][d];
        ss += cc * cc;
      }
    }
  const float norm2 = (float)sqrt(5.0 / ss);

  prep_kernel<<<109, 256, 0, stream>>>(Wm2, bm2, P0, P2, Wm1, W0e, W1o, W2e, ws, out);
  fused_kernel<<<2500, 256, 0, stream>>>(x_scalar, x_sph, bm1, ws, batch, out, norm2);
}

// Round 6
// 203.560 us; speedup vs baseline: 1.6192x; 1.6192x over previous
//
#include <hip/hip_runtime.h>
#include <math.h>

// ---------------- workspace layout (float offsets) ----------------
// W2P folded (v1+v4 -> one column): [64][192], row-major [c][o] so lane o is coalesced.
#define OFF_W2P 0              // [64][192]
#define OFF_B2P 12288          // [192]
#define WS_FLOATS 12480

#define SC_Y0 0.0180421959121758f   // (1/sqrt(32))*(1/sqrt(96))
#define SC_Y2 0.015625f             // (1/sqrt(32))*(1/sqrt(128))
#define S2f 0.70710678118654752f
#define S6f 0.40824829046386302f
#define TWOS2f 1.41421356237309505f
#define TWOS6f 0.81649658092772603f
#define ISQRT3 0.57735026918962576f
#define ISQRT5 0.44721359549995794f
#define H0SC 0.08838834764831845f   // 1/sqrt(128)
#define H1SC 0.125f                 // 1/sqrt(64)
#define H2SC 0.17677669529663689f   // 1/sqrt(32)

__device__ static inline float dot32(const float* __restrict__ a,
                                     const float* __restrict__ b) {
  const float4* a4 = (const float4*)a;
  const float4* b4 = (const float4*)b;
  float acc = 0.f;
#pragma unroll
  for (int q = 0; q < 8; ++q) {
    float4 x = a4[q], y = b4[q];
    acc += x.x * y.x + x.y * y.y + x.z * y.z + x.w * y.w;
  }
  return acc;
}

// ---------------- prep: folded W2P[c][o], B2P, zero out ----------------
// 6 folded columns s': {v0: k0*P0[0:32]*Y0}, {v15: k1*P2[0:32]*Y2 + k5*P2[64:96]*Y2},
// {v2: k2*P0[32:64]*Y0}, {v3: k4*P2[32:64]*Y2}, {v5: k6*P0[64:96]*Y0}, {v6: k8*P2[96:128]*Y2}
__global__ __launch_bounds__(256) void prep_kernel(
    const float* __restrict__ Wm2, const float* __restrict__ bm2,
    const float* __restrict__ P0, const float* __restrict__ P2,
    float* __restrict__ ws, float* __restrict__ out) {
  int j = blockIdx.x * 256 + threadIdx.x;
  if (j < 2304) out[j] = 0.f;

  if (j < 12288) {
    // W2P[c][o] at ws[j]: c = j/192, o = j%192, s = o>>5, u = o&31
    const int c = j / 192, o = j % 192;
    const int s = o >> 5, u = o & 31;
    int k; const float* P; float sc;
    switch (s) {
      case 0: k = 0; P = P0;      sc = SC_Y0; break;
      case 1: k = 1; P = P2;      sc = SC_Y2; break;
      case 2: k = 2; P = P0 + 32; sc = SC_Y0; break;
      case 3: k = 4; P = P2 + 32; sc = SC_Y2; break;
      case 4: k = 6; P = P0 + 64; sc = SC_Y0; break;
      default: k = 8; P = P2 + 96; sc = SC_Y2; break;
    }
    float acc = dot32(Wm2 + c * 9216 + k * 1024 + u * 32, P);
    if (s == 1) acc += dot32(Wm2 + c * 9216 + 5 * 1024 + u * 32, P2 + 64);
    ws[OFF_W2P + j] = acc * sc;
  } else if (j < 12480) {
    const int o = j - 12288;
    const int s = o >> 5, u = o & 31;
    int k; const float* P; float sc;
    switch (s) {
      case 0: k = 0; P = P0;      sc = SC_Y0; break;
      case 1: k = 1; P = P2;      sc = SC_Y2; break;
      case 2: k = 2; P = P0 + 32; sc = SC_Y0; break;
      case 3: k = 4; P = P2 + 32; sc = SC_Y2; break;
      case 4: k = 6; P = P0 + 64; sc = SC_Y0; break;
      default: k = 8; P = P2 + 96; sc = SC_Y2; break;
    }
    float acc = dot32(bm2 + k * 1024 + u * 32, P);
    if (s == 1) acc += dot32(bm2 + 5 * 1024 + u * 32, P2 + 64);
    ws[OFF_B2P + o] = acc * sc;
  }
}

// ---------------- fused: MLP + V + projections + path math + reduce, 8-node tile ----------------
// LDS 8384 B: Vt[8][192] + hi2[8][64] + sphs[8][6].
// Original weight layouts everywhere (lane-coalesced; round-5 lesson: per-THREAD-contiguous
// transposed layouts destroy per-WAVE coalescing). Global broadcast x reads (round-4 evidence).
// Phase 3 keeps peak live values ~20 floats (round-4 spill lesson). Bound (256,7): ~72-VGPR
// cap with margin over the ~50 this body needs; 7 blocks/CU.
__global__ __launch_bounds__(256, 7) void fused_kernel(
    const float* __restrict__ xs_g, const float* __restrict__ xsph,
    const float* __restrict__ W0e, const float* __restrict__ W1o,
    const float* __restrict__ W2e,
    const float* __restrict__ Wm1, const float* __restrict__ bm1,
    const float* __restrict__ ws, const int* __restrict__ batch,
    float* __restrict__ out, const float norm2) {
  __shared__ __align__(16) float Vt[8][192];
  __shared__ __align__(16) float hi2[8][64];
  __shared__ float sphs[8][6];

  const int tid = threadIdx.x;
  const int n0 = blockIdx.x * 8;

  // ---- phase 2: hidden = silu(x_scalar @ Wm1 + bm1): 8n x 64c; thread=(n=tid>>5, 2c) ----
  {
    const int n = tid >> 5, c0 = (tid & 31) * 2;
    const float* xr = xs_g + (size_t)(n0 + n) * 128;
    float acc0 = 0.f, acc1 = 0.f;
#pragma unroll 4
    for (int mq = 0; mq < 32; ++mq) {
      const float4 xv = *(const float4*)(xr + mq * 4);  // broadcast within half-wave
      const float xa[4] = {xv.x, xv.y, xv.z, xv.w};
#pragma unroll
      for (int r = 0; r < 4; ++r) {
        const float2 w = *(const float2*)(Wm1 + (mq * 4 + r) * 64 + c0);  // coalesced
        acc0 += xa[r] * w.x;
        acc1 += xa[r] * w.y;
      }
    }
    const float z0 = acc0 + bm1[c0];
    const float z1 = acc1 + bm1[c0 + 1];
    const float s0 = z0 / (1.f + __expf(-z0));
    const float s1 = z1 / (1.f + __expf(-z1));
    *(float2*)&hi2[n][c0] = make_float2(s0, s1);
  }
  __syncthreads();  // hi2 ready

  // ---- phase 3: V[n][o] = b2p[o] + sum_c hi2[n][c]*W2P[c][o]; thread=o (192 active) ----
  // Per 4-c chunk: 4 coalesced w loads + 8 broadcast float4 h loads + 32 FMA.
  // Peak live ~20 floats (acc[8]+4w+h4+ptrs) - deliberately below the round-4 spill trigger.
  if (tid < 192) {
    const int o = tid;
    float acc[8];
    {
      const float b = ws[OFF_B2P + o];
#pragma unroll
      for (int n = 0; n < 8; ++n) acc[n] = b;
    }
#pragma unroll 2
    for (int c4 = 0; c4 < 64; c4 += 4) {
      const float w0 = ws[OFF_W2P + (c4 + 0) * 192 + o];
      const float w1 = ws[OFF_W2P + (c4 + 1) * 192 + o];
      const float w2 = ws[OFF_W2P + (c4 + 2) * 192 + o];
      const float w3 = ws[OFF_W2P + (c4 + 3) * 192 + o];
#pragma unroll
      for (int n = 0; n < 8; ++n) {
        const float4 h = *(const float4*)&hi2[n][c4];  // broadcast
        acc[n] += h.x * w0 + h.y * w1 + h.z * w2 + h.w * w3;
      }
    }
#pragma unroll
    for (int n = 0; n < 8; ++n) Vt[n][o] = acc[n];
  }

  // ---- phase B: h0/h1/h2 from global x_sph (broadcast float4) + original weights ----
  const int u = tid & 31, ni = tid >> 5;
  const float* row = xsph + (size_t)(n0 + ni) * 480;

  float h0;
  {
    float a0 = 0.f;
#pragma unroll 4
    for (int mq = 0; mq < 32; ++mq) {
      const float4 xv = *(const float4*)(row + mq * 4);
      const float xa[4] = {xv.x, xv.y, xv.z, xv.w};
#pragma unroll
      for (int r = 0; r < 4; ++r) a0 += xa[r] * W0e[(mq * 4 + r) * 32 + u];  // coalesced
    }
    h0 = a0 * H0SC;
  }

  float h1a, h1b, h1c;
  {
    float a1[3] = {0.f, 0.f, 0.f};
#pragma unroll 2
    for (int mq = 0; mq < 16; ++mq) {
      const float4 b0 = *(const float4*)(row + 128 + mq * 12);
      const float4 b1 = *(const float4*)(row + 128 + mq * 12 + 4);
      const float4 b2 = *(const float4*)(row + 128 + mq * 12 + 8);
      const float xa[12] = {b0.x, b0.y, b0.z, b0.w, b1.x, b1.y, b1.z, b1.w,
                            b2.x, b2.y, b2.z, b2.w};
#pragma unroll
      for (int mm = 0; mm < 4; ++mm) {
        const float w = W1o[(mq * 4 + mm) * 32 + u];  // coalesced
#pragma unroll
        for (int j = 0; j < 3; ++j) a1[j] += xa[mm * 3 + j] * w;
      }
    }
    h1a = a1[0] * H1SC; h1b = a1[1] * H1SC; h1c = a1[2] * H1SC;
  }

  float h2v[5];
  {
    float a2[5] = {0.f, 0.f, 0.f, 0.f, 0.f};
#pragma unroll 2
    for (int mq = 0; mq < 8; ++mq) {
      const float4 c0v = *(const float4*)(row + 320 + mq * 20);
      const float4 c1v = *(const float4*)(row + 320 + mq * 20 + 4);
      const float4 c2v = *(const float4*)(row + 320 + mq * 20 + 8);
      const float4 c3v = *(const float4*)(row + 320 + mq * 20 + 12);
      const float4 c4v = *(const float4*)(row + 320 + mq * 20 + 16);
      const float xa[20] = {c0v.x, c0v.y, c0v.z, c0v.w, c1v.x, c1v.y, c1v.z, c1v.w,
                            c2v.x, c2v.y, c2v.z, c2v.w, c3v.x, c3v.y, c3v.z, c3v.w,
                            c4v.x, c4v.y, c4v.z, c4v.w};
#pragma unroll
      for (int mm = 0; mm < 4; ++mm) {
        const float w = W2e[(mq * 4 + mm) * 32 + u];  // coalesced
#pragma unroll
        for (int j = 0; j < 5; ++j) a2[j] += xa[mm * 5 + j] * w;
      }
    }
#pragma unroll
    for (int j = 0; j < 5; ++j) h2v[j] = a2[j] * H2SC;
  }
  __syncthreads();  // Vt ready

  // ---- phase D: path math + u-reduction (verbatim KD math; folded V columns) ----
  {
    const float* Vp = &Vt[ni][u];
    const float v0 = Vp[0], v15 = Vp[32], v2 = Vp[64], v3 = Vp[96];
    const float v5 = Vp[128], v6 = Vp[160];

    const float d11 = h1a * h1a + h1b * h1b + h1c * h1c;
    const float d22 = h2v[0] * h2v[0] + h2v[1] * h2v[1] + h2v[2] * h2v[2] +
                      h2v[3] * h2v[3] + h2v[4] * h2v[4];
    float y0 = v0 * h0 * h0 + v2 * d11 * ISQRT3 + v5 * d22 * ISQRT5;

    const float o00 = h1a * h1a, o01 = h1a * h1b, o02 = h1a * h1c;
    const float o11 = h1b * h1b, o12 = h1b * h1c, o22 = h1c * h1c;
    const float t40 = TWOS2f * o01, t41 = TWOS2f * o12;
    const float t42 = S6f * (2.f * o22 - o00 - o11);
    const float t43 = TWOS2f * o02, t44 = S2f * (o00 - o11);

    const float A00 = -S6f * h2v[2] + S2f * h2v[4];
    const float A01 = S2f * h2v[0];
    const float A02 = S2f * h2v[3];
    const float A11 = -S6f * h2v[2] - S2f * h2v[4];
    const float A12 = S2f * h2v[1];
    const float A22 = TWOS6f * h2v[2];
    const float B00 = A00 * A00 + A01 * A01 + A02 * A02;
    const float B01 = A00 * A01 + A01 * A11 + A02 * A12;
    const float B02 = A00 * A02 + A01 * A12 + A02 * A22;
    const float B11 = A01 * A01 + A11 * A11 + A12 * A12;
    const float B12 = A01 * A02 + A11 * A12 + A12 * A22;
    const float B22 = A02 * A02 + A12 * A12 + A22 * A22;
    const float t80 = TWOS2f * B01, t81 = TWOS2f * B12;
    const float t82 = S6f * (2.f * B22 - B00 - B11);
    const float t83 = TWOS2f * B02, t84 = S2f * (B00 - B11);

    const float w15 = v15 * h0;
    const float v6n = v6 * norm2;
    float y2r[5];
    y2r[0] = w15 * h2v[0] + v3 * t40 + v6n * t80;
    y2r[1] = w15 * h2v[1] + v3 * t41 + v6n * t81;
    y2r[2] = w15 * h2v[2] + v3 * t42 + v6n * t82;
    y2r[3] = w15 * h2v[3] + v3 * t43 + v6n * t83;
    y2r[4] = w15 * h2v[4] + v3 * t44 + v6n * t84;

#pragma unroll
    for (int off = 16; off > 0; off >>= 1) {
      y0 += __shfl_xor(y0, off, 32);
#pragma unroll
      for (int r = 0; r < 5; ++r) y2r[r] += __shfl_xor(y2r[r], off, 32);
    }

    if (u == 0) {
      sphs[ni][0] = y0;
#pragma unroll
      for (int r = 0; r < 5; ++r) sphs[ni][1 + r] = y2r[r];
    }
  }
  __syncthreads();

  // ---- phase E: Q-contract + segment atomics over the 8-node tile ----
  if (tid < 9) {
    const float QW[9][6] = {
        {ISQRT3, 0.f, 0.f, -S6f, 0.f, S2f},
        {0.f, S2f, 0.f, 0.f, 0.f, 0.f},
        {0.f, 0.f, 0.f, 0.f, S2f, 0.f},
        {0.f, S2f, 0.f, 0.f, 0.f, 0.f},
        {ISQRT3, 0.f, 0.f, -S6f, 0.f, -S2f},
        {0.f, 0.f, S2f, 0.f, 0.f, 0.f},
        {0.f, 0.f, 0.f, 0.f, S2f, 0.f},
        {0.f, 0.f, S2f, 0.f, 0.f, 0.f},
        {ISQRT3, 0.f, 0.f, TWOS6f, 0.f, 0.f}};
    const int a = tid / 3, b = tid % 3;
    const int rolled = ((a + 1) % 3) * 3 + ((b + 1) % 3);
    const float c0 = QW[tid][0], c1 = QW[tid][1], c2 = QW[tid][2];
    const float c3 = QW[tid][3], c4 = QW[tid][4], c5 = QW[tid][5];
    int cur_g = batch[n0];
    float acc = 0.f;
#pragma unroll
    for (int q = 0; q < 8; ++q) {
      const int g = batch[n0 + q];
      const float val = c0 * sphs[q][0] + c1 * sphs[q][1] + c2 * sphs[q][2] +
                        c3 * sphs[q][3] + c4 * sphs[q][4] + c5 * sphs[q][5];
      if (g != cur_g) {
        atomicAdd(out + cur_g * 9 + rolled, acc);
        acc = 0.f;
        cur_g = g;
      }
      acc += val;
    }
    atomicAdd(out + cur_g * 9 + rolled, acc);
  }
}

extern "C" void kernel_launch(void* const* d_in, const int* in_sizes, int n_in,
                              void* d_out, int out_size, void* d_ws, size_t ws_size,
                              hipStream_t stream) {
  const float* x_scalar = (const float*)d_in[0];
  const float* x_sph    = (const float*)d_in[1];
  const int*   batch    = (const int*)d_in[2];
  const float* W0e      = (const float*)d_in[3];
  const float* W1o      = (const float*)d_in[4];
  const float* W2e      = (const float*)d_in[5];
  const float* Wm1      = (const float*)d_in[6];
  const float* bm1      = (const float*)d_in[7];
  const float* Wm2      = (const float*)d_in[8];
  const float* bm2      = (const float*)d_in[9];
  const float* P0       = (const float*)d_in[10];
  // P1 (d_in[11]) provably unused: C111/C221 antisymmetric vs h(x)h of same h.
  const float* P2       = (const float*)d_in[12];
  float* ws  = (float*)d_ws;
  float* out = (float*)d_out;

  if (ws_size < (size_t)WS_FLOATS * sizeof(float)) return;

  // host-side C222 normalization (pure CPU double math; = sqrt(12/7))
  double Q2[5][3][3] = {};
  const double s2d = 0.70710678118654752440, s6d = 0.40824829046386301637;
  Q2[0][0][1] = Q2[0][1][0] = s2d;
  Q2[1][1][2] = Q2[1][2][1] = s2d;
  Q2[2][0][0] = Q2[2][1][1] = -s6d; Q2[2][2][2] = 2.0 * s6d;
  Q2[3][0][2] = Q2[3][2][0] = s2d;
  Q2[4][0][0] = s2d; Q2[4][1][1] = -s2d;
  double ss = 0.0;
  for (int i = 0; i < 5; ++i)
    for (int jj = 0; jj < 5; ++jj) {
      double S[3][3];
      for (int a = 0; a < 3; ++a)
        for (int d = 0; d < 3; ++d) {
          double m1 = 0, m2 = 0;
          for (int b = 0; b < 3; ++b) {
            m1 += Q2[i][a][b] * Q2[jj][d][b];
            m2 += Q2[i][d][b] * Q2[jj][a][b];
          }
          S[a][d] = 0.5 * (m1 + m2);
        }
      double tr = (S[0][0] + S[1][1] + S[2][2]) / 3.0;
      S[0][0] -= tr; S[1][1] -= tr; S[2][2] -= tr;
      for (int kk = 0; kk < 5; ++kk) {
        double cc = 0;
        for (int a = 0; a < 3; ++a)
          for (int d = 0; d < 3; ++d) cc += Q2[kk][a][d] * S[a][d];
        ss += cc * cc;
      }
    }
  const float norm2 = (float)sqrt(5.0 / ss);

  prep_kernel<<<49, 256, 0, stream>>>(Wm2, bm2, P0, P2, ws, out);
  fused_kernel<<<2500, 256, 0, stream>>>(x_scalar, x_sph, W0e, W1o, W2e,
                                         Wm1, bm1, ws, batch, out, norm2);
}

// Round 7
// 179.703 us; speedup vs baseline: 1.8341x; 1.1328x over previous
//
#include <hip/hip_runtime.h>
#include <math.h>

// ---------------- workspace layout (float offsets) ----------------
// W2P folded (v1+v4 -> one column): [64][192], row-major [c][o] so lane o is coalesced.
#define OFF_W2P 0              // [64][192]
#define OFF_B2P 12288          // [192]
#define WS_FLOATS 12480

#define SC_Y0 0.0180421959121758f   // (1/sqrt(32))*(1/sqrt(96))
#define SC_Y2 0.015625f             // (1/sqrt(32))*(1/sqrt(128))
#define S2f 0.70710678118654752f
#define S6f 0.40824829046386302f
#define TWOS2f 1.41421356237309505f
#define TWOS6f 0.81649658092772603f
#define ISQRT3 0.57735026918962576f
#define ISQRT5 0.44721359549995794f
#define H0SC 0.08838834764831845f   // 1/sqrt(128)
#define H1SC 0.125f                 // 1/sqrt(64)
#define H2SC 0.17677669529663689f   // 1/sqrt(32)

__device__ static inline float dot32(const float* __restrict__ a,
                                     const float* __restrict__ b) {
  const float4* a4 = (const float4*)a;
  const float4* b4 = (const float4*)b;
  float acc = 0.f;
#pragma unroll
  for (int q = 0; q < 8; ++q) {
    float4 x = a4[q], y = b4[q];
    acc += x.x * y.x + x.y * y.y + x.z * y.z + x.w * y.w;
  }
  return acc;
}

// ---------------- prep: folded W2P[c][o], B2P, zero out ----------------
// 6 folded columns s': {v0: k0*P0[0:32]*Y0}, {v15: k1*P2[0:32]*Y2 + k5*P2[64:96]*Y2},
// {v2: k2*P0[32:64]*Y0}, {v3: k4*P2[32:64]*Y2}, {v5: k6*P0[64:96]*Y0}, {v6: k8*P2[96:128]*Y2}
__global__ __launch_bounds__(256) void prep_kernel(
    const float* __restrict__ Wm2, const float* __restrict__ bm2,
    const float* __restrict__ P0, const float* __restrict__ P2,
    float* __restrict__ ws, float* __restrict__ out) {
  int j = blockIdx.x * 256 + threadIdx.x;
  if (j < 2304) out[j] = 0.f;

  if (j < 12288) {
    // W2P[c][o] at ws[j]: c = j/192, o = j%192, s = o>>5, u = o&31
    const int c = j / 192, o = j % 192;
    const int s = o >> 5, u = o & 31;
    int k; const float* P; float sc;
    switch (s) {
      case 0: k = 0; P = P0;      sc = SC_Y0; break;
      case 1: k = 1; P = P2;      sc = SC_Y2; break;
      case 2: k = 2; P = P0 + 32; sc = SC_Y0; break;
      case 3: k = 4; P = P2 + 32; sc = SC_Y2; break;
      case 4: k = 6; P = P0 + 64; sc = SC_Y0; break;
      default: k = 8; P = P2 + 96; sc = SC_Y2; break;
    }
    float acc = dot32(Wm2 + c * 9216 + k * 1024 + u * 32, P);
    if (s == 1) acc += dot32(Wm2 + c * 9216 + 5 * 1024 + u * 32, P2 + 64);
    ws[OFF_W2P + j] = acc * sc;
  } else if (j < 12480) {
    const int o = j - 12288;
    const int s = o >> 5, u = o & 31;
    int k; const float* P; float sc;
    switch (s) {
      case 0: k = 0; P = P0;      sc = SC_Y0; break;
      case 1: k = 1; P = P2;      sc = SC_Y2; break;
      case 2: k = 2; P = P0 + 32; sc = SC_Y0; break;
      case 3: k = 4; P = P2 + 32; sc = SC_Y2; break;
      case 4: k = 6; P = P0 + 64; sc = SC_Y0; break;
      default: k = 8; P = P2 + 96; sc = SC_Y2; break;
    }
    float acc = dot32(bm2 + k * 1024 + u * 32, P);
    if (s == 1) acc += dot32(bm2 + 5 * 1024 + u * 32, P2 + 64);
    ws[OFF_B2P + o] = acc * sc;
  }
}

// ---------------- fused: MLP + V + projections + path math + reduce, 8-node tile ----------------
// LDS 17728 B -> 8 blocks/CU (the 32-wave cap):
//   [0, 3872)      : xp[8][484]  (x_sph staging; R6-vs-R3 isolated: staging = -40us)
//                    ... overlaid by Vt[8][192] AFTER phase B consumes xp
//   [3872, 4384)   : hi2[8][64]
//   [4384, 4432)   : sphs[8][6]
// x_scalar read from global (broadcast; minor traffic). Original weight layouts
// (R5 lesson: wave coalescing, never per-thread transposes). Staging issued into
// registers BEFORE phase 2, ds_write after (T14 split: phase-2 compute hides HBM lat).
// Peak live ~50 floats -> (256,8) 64-VGPR cap without spill (R4 lesson: stay well below).
__global__ __launch_bounds__(256, 8) void fused_kernel(
    const float* __restrict__ xs_g, const float* __restrict__ xsph,
    const float* __restrict__ W0e, const float* __restrict__ W1o,
    const float* __restrict__ W2e,
    const float* __restrict__ Wm1, const float* __restrict__ bm1,
    const float* __restrict__ ws, const int* __restrict__ batch,
    float* __restrict__ out, const float norm2) {
  __shared__ __align__(16) float smem[4432];
  float (*xp)[484] = (float (*)[484])smem;
  float (*Vt)[192] = (float (*)[192])smem;          // overlays xp after phase B
  float (*hi2)[64] = (float (*)[64])(smem + 3872);
  float (*sphs)[6] = (float (*)[6])(smem + 4384);

  const int tid = threadIdx.x;
  const int n0 = blockIdx.x * 8;

  // ---- stage-issue: 4 float4 of x_sph per thread into named registers (960 total) ----
  const int i0 = tid, i1 = tid + 256, i2 = tid + 512, i3 = tid + 768;
  float4 st0, st1, st2, st3;
  {
    const int r0 = i0 / 120, c0_ = i0 % 120;
    const int r1 = i1 / 120, c1_ = i1 % 120;
    const int r2 = i2 / 120, c2_ = i2 % 120;
    st0 = *(const float4*)(xsph + (size_t)(n0 + r0) * 480 + c0_ * 4);
    st1 = *(const float4*)(xsph + (size_t)(n0 + r1) * 480 + c1_ * 4);
    st2 = *(const float4*)(xsph + (size_t)(n0 + r2) * 480 + c2_ * 4);
    if (tid < 192) {
      const int r3 = i3 / 120, c3_ = i3 % 120;
      st3 = *(const float4*)(xsph + (size_t)(n0 + r3) * 480 + c3_ * 4);
    }
  }

  // ---- phase 2 (overlaps staging loads): hidden = silu(x_scalar @ Wm1 + bm1) ----
  // thread = (n = tid>>5, channels c0,c0+1); 2 independent chains per output.
  {
    const int n = tid >> 5, c0 = (tid & 31) * 2;
    const float* xr = xs_g + (size_t)(n0 + n) * 128;
    float p0 = 0.f, p1 = 0.f, q0 = 0.f, q1 = 0.f;
#pragma unroll 4
    for (int mq = 0; mq < 32; ++mq) {
      const float4 xv = *(const float4*)(xr + mq * 4);  // broadcast per half-wave
      const float2 w0 = *(const float2*)(Wm1 + (mq * 4 + 0) * 64 + c0);  // coalesced
      const float2 w1 = *(const float2*)(Wm1 + (mq * 4 + 1) * 64 + c0);
      const float2 w2 = *(const float2*)(Wm1 + (mq * 4 + 2) * 64 + c0);
      const float2 w3 = *(const float2*)(Wm1 + (mq * 4 + 3) * 64 + c0);
      p0 += xv.x * w0.x; q0 += xv.y * w1.x; p0 += xv.z * w2.x; q0 += xv.w * w3.x;
      p1 += xv.x * w0.y; q1 += xv.y * w1.y; p1 += xv.z * w2.y; q1 += xv.w * w3.y;
    }
    const float z0 = p0 + q0 + bm1[c0];
    const float z1 = p1 + q1 + bm1[c0 + 1];
    const float s0 = z0 / (1.f + __expf(-z0));
    const float s1 = z1 / (1.f + __expf(-z1));
    *(float2*)&hi2[n][c0] = make_float2(s0, s1);
  }

  // ---- stage-write: commit x_sph registers to LDS ----
  {
    const int r0 = i0 / 120, c0_ = i0 % 120;
    const int r1 = i1 / 120, c1_ = i1 % 120;
    const int r2 = i2 / 120, c2_ = i2 % 120;
    *(float4*)&xp[r0][c0_ * 4] = st0;
    *(float4*)&xp[r1][c1_ * 4] = st1;
    *(float4*)&xp[r2][c2_ * 4] = st2;
    if (tid < 192) {
      const int r3 = i3 / 120, c3_ = i3 % 120;
      *(float4*)&xp[r3][c3_ * 4] = st3;
    }
  }
  __syncthreads();  // xp + hi2 ready

  // ---- phase B: h0/h1/h2 from xp (LDS broadcast) + original coalesced weights ----
  const int u = tid & 31, ni = tid >> 5;
  const float* row = xp[ni];

  float h0;
  {
    float a00 = 0.f, a01 = 0.f;  // 2 chains
#pragma unroll 4
    for (int mq = 0; mq < 32; ++mq) {
      const float4 xv = *(const float4*)(row + mq * 4);
      a00 += xv.x * W0e[(mq * 4 + 0) * 32 + u];
      a01 += xv.y * W0e[(mq * 4 + 1) * 32 + u];
      a00 += xv.z * W0e[(mq * 4 + 2) * 32 + u];
      a01 += xv.w * W0e[(mq * 4 + 3) * 32 + u];
    }
    h0 = (a00 + a01) * H0SC;
  }

  float h1a, h1b, h1c;
  {
    float a1[3] = {0.f, 0.f, 0.f};
#pragma unroll 2
    for (int mq = 0; mq < 16; ++mq) {
      const float4 b0 = *(const float4*)(row + 128 + mq * 12);
      const float4 b1 = *(const float4*)(row + 128 + mq * 12 + 4);
      const float4 b2 = *(const float4*)(row + 128 + mq * 12 + 8);
      const float xa[12] = {b0.x, b0.y, b0.z, b0.w, b1.x, b1.y, b1.z, b1.w,
                            b2.x, b2.y, b2.z, b2.w};
#pragma unroll
      for (int mm = 0; mm < 4; ++mm) {
        const float w = W1o[(mq * 4 + mm) * 32 + u];  // coalesced
#pragma unroll
        for (int j = 0; j < 3; ++j) a1[j] += xa[mm * 3 + j] * w;
      }
    }
    h1a = a1[0] * H1SC; h1b = a1[1] * H1SC; h1c = a1[2] * H1SC;
  }

  float h2v[5];
  {
    float a2[5] = {0.f, 0.f, 0.f, 0.f, 0.f};
#pragma unroll 2
    for (int mq = 0; mq < 8; ++mq) {
      const float4 c0v = *(const float4*)(row + 320 + mq * 20);
      const float4 c1v = *(const float4*)(row + 320 + mq * 20 + 4);
      const float4 c2v = *(const float4*)(row + 320 + mq * 20 + 8);
      const float4 c3v = *(const float4*)(row + 320 + mq * 20 + 12);
      const float4 c4v = *(const float4*)(row + 320 + mq * 20 + 16);
      const float xa[20] = {c0v.x, c0v.y, c0v.z, c0v.w, c1v.x, c1v.y, c1v.z, c1v.w,
                            c2v.x, c2v.y, c2v.z, c2v.w, c3v.x, c3v.y, c3v.z, c3v.w,
                            c4v.x, c4v.y, c4v.z, c4v.w};
#pragma unroll
      for (int mm = 0; mm < 4; ++mm) {
        const float w = W2e[(mq * 4 + mm) * 32 + u];  // coalesced
#pragma unroll
        for (int j = 0; j < 5; ++j) a2[j] += xa[mm * 5 + j] * w;
      }
    }
#pragma unroll
    for (int j = 0; j < 5; ++j) h2v[j] = a2[j] * H2SC;
  }
  __syncthreads();  // xp fully consumed -> Vt may overlay

  // ---- phase 3: V[n][o] = b2p[o] + sum_c hi2[n][c]*W2P[c][o]; thread=o (192 active) ----
  if (tid < 192) {
    const int o = tid;
    float acc[8];
    {
      const float b = ws[OFF_B2P + o];
#pragma unroll
      for (int n = 0; n < 8; ++n) acc[n] = b;
    }
#pragma unroll 2
    for (int c4 = 0; c4 < 64; c4 += 4) {
      const float w0 = ws[OFF_W2P + (c4 + 0) * 192 + o];  // coalesced, L1-resident
      const float w1 = ws[OFF_W2P + (c4 + 1) * 192 + o];
      const float w2 = ws[OFF_W2P + (c4 + 2) * 192 + o];
      const float w3 = ws[OFF_W2P + (c4 + 3) * 192 + o];
#pragma unroll
      for (int n = 0; n < 8; ++n) {
        const float4 h = *(const float4*)&hi2[n][c4];  // broadcast
        acc[n] += h.x * w0 + h.y * w1 + h.z * w2 + h.w * w3;
      }
    }
#pragma unroll
    for (int n = 0; n < 8; ++n) Vt[n][o] = acc[n];
  }
  __syncthreads();  // Vt ready

  // ---- phase D: path math + u-reduction (verbatim; folded V columns) ----
  {
    const float* Vp = &Vt[ni][u];
    const float v0 = Vp[0], v15 = Vp[32], v2 = Vp[64], v3 = Vp[96];
    const float v5 = Vp[128], v6 = Vp[160];

    const float d11 = h1a * h1a + h1b * h1b + h1c * h1c;
    const float d22 = h2v[0] * h2v[0] + h2v[1] * h2v[1] + h2v[2] * h2v[2] +
                      h2v[3] * h2v[3] + h2v[4] * h2v[4];
    float y0 = v0 * h0 * h0 + v2 * d11 * ISQRT3 + v5 * d22 * ISQRT5;

    const float o00 = h1a * h1a, o01 = h1a * h1b, o02 = h1a * h1c;
    const float o11 = h1b * h1b, o12 = h1b * h1c, o22 = h1c * h1c;
    const float t40 = TWOS2f * o01, t41 = TWOS2f * o12;
    const float t42 = S6f * (2.f * o22 - o00 - o11);
    const float t43 = TWOS2f * o02, t44 = S2f * (o00 - o11);

    const float A00 = -S6f * h2v[2] + S2f * h2v[4];
    const float A01 = S2f * h2v[0];
    const float A02 = S2f * h2v[3];
    const float A11 = -S6f * h2v[2] - S2f * h2v[4];
    const float A12 = S2f * h2v[1];
    const float A22 = TWOS6f * h2v[2];
    const float B00 = A00 * A00 + A01 * A01 + A02 * A02;
    const float B01 = A00 * A01 + A01 * A11 + A02 * A12;
    const float B02 = A00 * A02 + A01 * A12 + A02 * A22;
    const float B11 = A01 * A01 + A11 * A11 + A12 * A12;
    const float B12 = A01 * A02 + A11 * A12 + A12 * A22;
    const float B22 = A02 * A02 + A12 * A12 + A22 * A22;
    const float t80 = TWOS2f * B01, t81 = TWOS2f * B12;
    const float t82 = S6f * (2.f * B22 - B00 - B11);
    const float t83 = TWOS2f * B02, t84 = S2f * (B00 - B11);

    const float w15 = v15 * h0;
    const float v6n = v6 * norm2;
    float y2r[5];
    y2r[0] = w15 * h2v[0] + v3 * t40 + v6n * t80;
    y2r[1] = w15 * h2v[1] + v3 * t41 + v6n * t81;
    y2r[2] = w15 * h2v[2] + v3 * t42 + v6n * t82;
    y2r[3] = w15 * h2v[3] + v3 * t43 + v6n * t83;
    y2r[4] = w15 * h2v[4] + v3 * t44 + v6n * t84;

#pragma unroll
    for (int off = 16; off > 0; off >>= 1) {
      y0 += __shfl_xor(y0, off, 32);
#pragma unroll
      for (int r = 0; r < 5; ++r) y2r[r] += __shfl_xor(y2r[r], off, 32);
    }

    if (u == 0) {
      sphs[ni][0] = y0;
#pragma unroll
      for (int r = 0; r < 5; ++r) sphs[ni][1 + r] = y2r[r];
    }
  }
  __syncthreads();

  // ---- phase E: Q-contract + segment atomics over the 8-node tile ----
  if (tid < 9) {
    const float QW[9][6] = {
        {ISQRT3, 0.f, 0.f, -S6f, 0.f, S2f},
        {0.f, S2f, 0.f, 0.f, 0.f, 0.f},
        {0.f, 0.f, 0.f, 0.f, S2f, 0.f},
        {0.f, S2f, 0.f, 0.f, 0.f, 0.f},
        {ISQRT3, 0.f, 0.f, -S6f, 0.f, -S2f},
        {0.f, 0.f, S2f, 0.f, 0.f, 0.f},
        {0.f, 0.f, 0.f, 0.f, S2f, 0.f},
        {0.f, 0.f, S2f, 0.f, 0.f, 0.f},
        {ISQRT3, 0.f, 0.f, TWOS6f, 0.f, 0.f}};
    const int a = tid / 3, b = tid % 3;
    const int rolled = ((a + 1) % 3) * 3 + ((b + 1) % 3);
    const float c0 = QW[tid][0], c1 = QW[tid][1], c2 = QW[tid][2];
    const float c3 = QW[tid][3], c4 = QW[tid][4], c5 = QW[tid][5];
    int cur_g = batch[n0];
    float acc = 0.f;
#pragma unroll
    for (int q = 0; q < 8; ++q) {
      const int g = batch[n0 + q];
      const float val = c0 * sphs[q][0] + c1 * sphs[q][1] + c2 * sphs[q][2] +
                        c3 * sphs[q][3] + c4 * sphs[q][4] + c5 * sphs[q][5];
      if (g != cur_g) {
        atomicAdd(out + cur_g * 9 + rolled, acc);
        acc = 0.f;
        cur_g = g;
      }
      acc += val;
    }
    atomicAdd(out + cur_g * 9 + rolled, acc);
  }
}

extern "C" void kernel_launch(void* const* d_in, const int* in_sizes, int n_in,
                              void* d_out, int out_size, void* d_ws, size_t ws_size,
                              hipStream_t stream) {
  const float* x_scalar = (const float*)d_in[0];
  const float* x_sph    = (const float*)d_in[1];
  const int*   batch    = (const int*)d_in[2];
  const float* W0e      = (const float*)d_in[3];
  const float* W1o      = (const float*)d_in[4];
  const float* W2e      = (const float*)d_in[5];
  const float* Wm1      = (const float*)d_in[6];
  const float* bm1      = (const float*)d_in[7];
  const float* Wm2      = (const float*)d_in[8];
  const float* bm2      = (const float*)d_in[9];
  const float* P0       = (const float*)d_in[10];
  // P1 (d_in[11]) provably unused: C111/C221 antisymmetric vs h(x)h of same h.
  const float* P2       = (const float*)d_in[12];
  float* ws  = (float*)d_ws;
  float* out = (float*)d_out;

  if (ws_size < (size_t)WS_FLOATS * sizeof(float)) return;

  // host-side C222 normalization (pure CPU double math; = sqrt(12/7))
  double Q2[5][3][3] = {};
  const double s2d = 0.70710678118654752440, s6d = 0.40824829046386301637;
  Q2[0][0][1] = Q2[0][1][0] = s2d;
  Q2[1][1][2] = Q2[1][2][1] = s2d;
  Q2[2][0][0] = Q2[2][1][1] = -s6d; Q2[2][2][2] = 2.0 * s6d;
  Q2[3][0][2] = Q2[3][2][0] = s2d;
  Q2[4][0][0] = s2d; Q2[4][1][1] = -s2d;
  double ss = 0.0;
  for (int i = 0; i < 5; ++i)
    for (int jj = 0; jj < 5; ++jj) {
      double S[3][3];
      for (int a = 0; a < 3; ++a)
        for (int d = 0; d < 3; ++d) {
          double m1 = 0, m2 = 0;
          for (int b = 0; b < 3; ++b) {
            m1 += Q2[i][a][b] * Q2[jj][d][b];
            m2 += Q2[i][d][b] * Q2[jj][a][b];
          }
          S[a][d] = 0.5 * (m1 + m2);
        }
      double tr = (S[0][0] + S[1][1] + S[2][2]) / 3.0;
      S[0][0] -= tr; S[1][1] -= tr; S[2][2] -= tr;
      for (int kk = 0; kk < 5; ++kk) {
        double cc = 0;
        for (int a = 0; a < 3; ++a)
          for (int d = 0; d < 3; ++d) cc += Q2[kk][a][d] * S[a][d];
        ss += cc * cc;
      }
    }
  const float norm2 = (float)sqrt(5.0 / ss);

  prep_kernel<<<49, 256, 0, stream>>>(Wm2, bm2, P0, P2, ws, out);
  fused_kernel<<<2500, 256, 0, stream>>>(x_scalar, x_sph, W0e, W1o, W2e,
                                         Wm1, bm1, ws, batch, out, norm2);
}

// Round 8
// 153.036 us; speedup vs baseline: 2.1537x; 1.1743x over previous
//
#include <hip/hip_runtime.h>
#include <math.h>

// ---------------- workspace layout (float offsets) ----------------
// W2P folded (v1+v4 -> one column): [64][192], row-major [c][o] so lane o is coalesced.
#define OFF_W2P 0              // [64][192]
#define OFF_B2P 12288          // [192]
#define WS_FLOATS 12480

#define SC_Y0 0.0180421959121758f   // (1/sqrt(32))*(1/sqrt(96))
#define SC_Y2 0.015625f             // (1/sqrt(32))*(1/sqrt(128))
#define S2f 0.70710678118654752f
#define S6f 0.40824829046386302f
#define TWOS2f 1.41421356237309505f
#define TWOS6f 0.81649658092772603f
#define ISQRT3 0.57735026918962576f
#define ISQRT5 0.44721359549995794f
#define H0SC 0.08838834764831845f   // 1/sqrt(128)
#define H1SC 0.125f                 // 1/sqrt(64)
#define H2SC 0.17677669529663689f   // 1/sqrt(32)

__device__ static inline float dot32(const float* __restrict__ a,
                                     const float* __restrict__ b) {
  const float4* a4 = (const float4*)a;
  const float4* b4 = (const float4*)b;
  float acc = 0.f;
#pragma unroll
  for (int q = 0; q < 8; ++q) {
    float4 x = a4[q], y = b4[q];
    acc += x.x * y.x + x.y * y.y + x.z * y.z + x.w * y.w;
  }
  return acc;
}

// ---------------- prep: folded W2P[c][o], B2P, zero out ----------------
__global__ __launch_bounds__(256) void prep_kernel(
    const float* __restrict__ Wm2, const float* __restrict__ bm2,
    const float* __restrict__ P0, const float* __restrict__ P2,
    float* __restrict__ ws, float* __restrict__ out) {
  int j = blockIdx.x * 256 + threadIdx.x;
  if (j < 2304) out[j] = 0.f;

  if (j < 12288) {
    const int c = j / 192, o = j % 192;
    const int s = o >> 5, u = o & 31;
    int k; const float* P; float sc;
    switch (s) {
      case 0: k = 0; P = P0;      sc = SC_Y0; break;
      case 1: k = 1; P = P2;      sc = SC_Y2; break;
      case 2: k = 2; P = P0 + 32; sc = SC_Y0; break;
      case 3: k = 4; P = P2 + 32; sc = SC_Y2; break;
      case 4: k = 6; P = P0 + 64; sc = SC_Y0; break;
      default: k = 8; P = P2 + 96; sc = SC_Y2; break;
    }
    float acc = dot32(Wm2 + c * 9216 + k * 1024 + u * 32, P);
    if (s == 1) acc += dot32(Wm2 + c * 9216 + 5 * 1024 + u * 32, P2 + 64);
    ws[OFF_W2P + j] = acc * sc;
  } else if (j < 12480) {
    const int o = j - 12288;
    const int s = o >> 5, u = o & 31;
    int k; const float* P; float sc;
    switch (s) {
      case 0: k = 0; P = P0;      sc = SC_Y0; break;
      case 1: k = 1; P = P2;      sc = SC_Y2; break;
      case 2: k = 2; P = P0 + 32; sc = SC_Y0; break;
      case 3: k = 4; P = P2 + 32; sc = SC_Y2; break;
      case 4: k = 6; P = P0 + 64; sc = SC_Y0; break;
      default: k = 8; P = P2 + 96; sc = SC_Y2; break;
    }
    float acc = dot32(bm2 + k * 1024 + u * 32, P);
    if (s == 1) acc += dot32(bm2 + 5 * 1024 + u * 32, P2 + 64);
    ws[OFF_B2P + o] = acc * sc;
  }
}

// ---------------- fused: 16-node tile, 2-node/thread weight reuse ----------------
// Cross-round evidence: VALU busy-time constant ~25us; time tracks per-node LOAD count,
// not occupancy (R3 52%/83us < R7 69%/95us). So this round maximizes FMA-per-load:
//   phase 2: 1n x 4ch (float4 w)      = 3.2 FMA/load  (R7: 1.6)
//   phase B: 2 nodes per thread       = 2.1 FMA/load  (R7: 1.05)
//   phase 3: acc[16] nodes per thread = 64 w-loads for 16 nodes
// LDS 37.2 KB: xp[16][512] (staged x_sph; R6: staging = -40us) + hi2[16][64] + sphs[16][6];
// Vt[16][192] overlays dead xp after phase B. T14 split staging (regs early, ds_write late).
// (256,4): 128-VGPR cap, ~2x headroom over the ~80 needed (R2/R4 spill lesson).
__global__ __launch_bounds__(256, 4) void fused_kernel(
    const float* __restrict__ xs_g, const float* __restrict__ xsph,
    const float* __restrict__ W0e, const float* __restrict__ W1o,
    const float* __restrict__ W2e,
    const float* __restrict__ Wm1, const float* __restrict__ bm1,
    const float* __restrict__ ws, const int* __restrict__ batch,
    float* __restrict__ out, const float norm2) {
  __shared__ __align__(16) float smem[9312];
  float (*xp)[512] = (float (*)[512])smem;          // [16][512], data in [0,480)
  float (*Vt)[192] = (float (*)[192])smem;          // overlays xp after phase B
  float (*hi2)[64] = (float (*)[64])(smem + 8192);
  float (*sphs)[6] = (float (*)[6])(smem + 9216);

  const int tid = threadIdx.x;
  const int n0 = blockIdx.x * 16;

  // ---- stage-issue: x_sph (16x480 = 1920 float4) into registers; 7-8 per thread ----
  float4 st[7];
  float4 st7;
#pragma unroll
  for (int k = 0; k < 7; ++k) {
    const int d = tid + k * 256;                 // float4 index into 16x120 data
    const int r = d / 120, c = d % 120;
    st[k] = *(const float4*)(xsph + (size_t)(n0 + r) * 480 + c * 4);
  }
  if (tid < 128) {
    const int d = tid + 1792;
    const int r = d / 120, c = d % 120;
    st7 = *(const float4*)(xsph + (size_t)(n0 + r) * 480 + c * 4);
  }

  // ---- phase 2 (hides staging latency): hidden = silu(x_scalar @ Wm1 + bm1) ----
  // thread = (n = tid>>4, channels c0..c0+3); float4 weight rows, 512 FMA / 160 loads.
  {
    const int n = tid >> 4, c0 = (tid & 15) * 4;
    const float* xr = xs_g + (size_t)(n0 + n) * 128;
    float a0 = 0.f, a1 = 0.f, a2 = 0.f, a3 = 0.f;
#pragma unroll 4
    for (int mq = 0; mq < 32; ++mq) {
      const float4 xv = *(const float4*)(xr + mq * 4);   // broadcast per 16 lanes
      const float4 w0 = *(const float4*)(Wm1 + (mq * 4 + 0) * 64 + c0);
      const float4 w1 = *(const float4*)(Wm1 + (mq * 4 + 1) * 64 + c0);
      const float4 w2 = *(const float4*)(Wm1 + (mq * 4 + 2) * 64 + c0);
      const float4 w3 = *(const float4*)(Wm1 + (mq * 4 + 3) * 64 + c0);
      a0 += xv.x * w0.x + xv.y * w1.x + xv.z * w2.x + xv.w * w3.x;
      a1 += xv.x * w0.y + xv.y * w1.y + xv.z * w2.y + xv.w * w3.y;
      a2 += xv.x * w0.z + xv.y * w1.z + xv.z * w2.z + xv.w * w3.z;
      a3 += xv.x * w0.w + xv.y * w1.w + xv.z * w2.w + xv.w * w3.w;
    }
    const float4 bb = *(const float4*)(bm1 + c0);
    const float z0 = a0 + bb.x, z1 = a1 + bb.y, z2 = a2 + bb.z, z3 = a3 + bb.w;
    float4 s;
    s.x = z0 / (1.f + __expf(-z0));
    s.y = z1 / (1.f + __expf(-z1));
    s.z = z2 / (1.f + __expf(-z2));
    s.w = z3 / (1.f + __expf(-z3));
    *(float4*)&hi2[n][c0] = s;
  }

  // ---- stage-write: commit x_sph registers to LDS (padded rows, stride 512) ----
#pragma unroll
  for (int k = 0; k < 7; ++k) {
    const int d = tid + k * 256;
    const int r = d / 120, c = d % 120;
    *(float4*)&xp[r][c * 4] = st[k];
  }
  if (tid < 128) {
    const int d = tid + 1792;
    const int r = d / 120, c = d % 120;
    *(float4*)&xp[r][c * 4] = st7;
  }
  __syncthreads();  // xp + hi2 ready

  // ---- phase B: h0/h1/h2 for TWO nodes per thread (weight reuse x2) ----
  const int u = tid & 31, ni = tid >> 5;     // nodes ni and ni+8
  const float* rowA = xp[ni];
  const float* rowB = xp[ni + 8];

  float h0A, h0B;
  {
    float aA = 0.f, aB = 0.f;
#pragma unroll 4
    for (int mq = 0; mq < 32; ++mq) {
      const float4 xa = *(const float4*)(rowA + mq * 4);
      const float4 xb = *(const float4*)(rowB + mq * 4);
      const float w0 = W0e[(mq * 4 + 0) * 32 + u];   // coalesced; feeds 2 FMAs
      const float w1 = W0e[(mq * 4 + 1) * 32 + u];
      const float w2 = W0e[(mq * 4 + 2) * 32 + u];
      const float w3 = W0e[(mq * 4 + 3) * 32 + u];
      aA += xa.x * w0 + xa.y * w1 + xa.z * w2 + xa.w * w3;
      aB += xb.x * w0 + xb.y * w1 + xb.z * w2 + xb.w * w3;
    }
    h0A = aA * H0SC; h0B = aB * H0SC;
  }

  float h1A[3], h1B[3];
  {
    float aA[3] = {0.f, 0.f, 0.f}, aB[3] = {0.f, 0.f, 0.f};
#pragma unroll 2
    for (int mq = 0; mq < 16; ++mq) {
      const float4 a0 = *(const float4*)(rowA + 128 + mq * 12);
      const float4 a1 = *(const float4*)(rowA + 128 + mq * 12 + 4);
      const float4 a2 = *(const float4*)(rowA + 128 + mq * 12 + 8);
      const float4 b0 = *(const float4*)(rowB + 128 + mq * 12);
      const float4 b1 = *(const float4*)(rowB + 128 + mq * 12 + 4);
      const float4 b2 = *(const float4*)(rowB + 128 + mq * 12 + 8);
      const float xa[12] = {a0.x, a0.y, a0.z, a0.w, a1.x, a1.y, a1.z, a1.w,
                            a2.x, a2.y, a2.z, a2.w};
      const float xb[12] = {b0.x, b0.y, b0.z, b0.w, b1.x, b1.y, b1.z, b1.w,
                            b2.x, b2.y, b2.z, b2.w};
#pragma unroll
      for (int mm = 0; mm < 4; ++mm) {
        const float w = W1o[(mq * 4 + mm) * 32 + u];
#pragma unroll
        for (int j = 0; j < 3; ++j) {
          aA[j] += xa[mm * 3 + j] * w;
          aB[j] += xb[mm * 3 + j] * w;
        }
      }
    }
#pragma unroll
    for (int j = 0; j < 3; ++j) { h1A[j] = aA[j] * H1SC; h1B[j] = aB[j] * H1SC; }
  }

  float h2A[5], h2B[5];
  {
    float aA[5] = {0.f, 0.f, 0.f, 0.f, 0.f}, aB[5] = {0.f, 0.f, 0.f, 0.f, 0.f};
#pragma unroll 2
    for (int mq = 0; mq < 8; ++mq) {
      const float4 a0 = *(const float4*)(rowA + 320 + mq * 20);
      const float4 a1 = *(const float4*)(rowA + 320 + mq * 20 + 4);
      const float4 a2 = *(const float4*)(rowA + 320 + mq * 20 + 8);
      const float4 a3 = *(const float4*)(rowA + 320 + mq * 20 + 12);
      const float4 a4 = *(const float4*)(rowA + 320 + mq * 20 + 16);
      const float4 b0 = *(const float4*)(rowB + 320 + mq * 20);
      const float4 b1 = *(const float4*)(rowB + 320 + mq * 20 + 4);
      const float4 b2 = *(const float4*)(rowB + 320 + mq * 20 + 8);
      const float4 b3 = *(const float4*)(rowB + 320 + mq * 20 + 12);
      const float4 b4 = *(const float4*)(rowB + 320 + mq * 20 + 16);
      const float xa[20] = {a0.x, a0.y, a0.z, a0.w, a1.x, a1.y, a1.z, a1.w,
                            a2.x, a2.y, a2.z, a2.w, a3.x, a3.y, a3.z, a3.w,
                            a4.x, a4.y, a4.z, a4.w};
      const float xb[20] = {b0.x, b0.y, b0.z, b0.w, b1.x, b1.y, b1.z, b1.w,
                            b2.x, b2.y, b2.z, b2.w, b3.x, b3.y, b3.z, b3.w,
                            b4.x, b4.y, b4.z, b4.w};
#pragma unroll
      for (int mm = 0; mm < 4; ++mm) {
        const float w = W2e[(mq * 4 + mm) * 32 + u];
#pragma unroll
        for (int j = 0; j < 5; ++j) {
          aA[j] += xa[mm * 5 + j] * w;
          aB[j] += xb[mm * 5 + j] * w;
        }
      }
    }
#pragma unroll
    for (int j = 0; j < 5; ++j) { h2A[j] = aA[j] * H2SC; h2B[j] = aB[j] * H2SC; }
  }
  __syncthreads();  // xp fully consumed -> Vt may overlay

  // ---- phase 3: V[n][o] = b2p[o] + sum_c hi2[n][c]*W2P[c][o]; 16 nodes/thread ----
  if (tid < 192) {
    const int o = tid;
    float acc[16];
    {
      const float b = ws[OFF_B2P + o];
#pragma unroll
      for (int n = 0; n < 16; ++n) acc[n] = b;
    }
    for (int c4 = 0; c4 < 64; c4 += 4) {
      const float w0 = ws[OFF_W2P + (c4 + 0) * 192 + o];  // coalesced; feeds 16 FMAs
      const float w1 = ws[OFF_W2P + (c4 + 1) * 192 + o];
      const float w2 = ws[OFF_W2P + (c4 + 2) * 192 + o];
      const float w3 = ws[OFF_W2P + (c4 + 3) * 192 + o];
#pragma unroll
      for (int n = 0; n < 16; ++n) {
        const float4 h = *(const float4*)&hi2[n][c4];     // broadcast
        acc[n] += h.x * w0 + h.y * w1 + h.z * w2 + h.w * w3;
      }
    }
#pragma unroll
    for (int n = 0; n < 16; ++n) Vt[n][o] = acc[n];
  }
  __syncthreads();  // Vt ready

  // ---- phase D: path math + u-reduction for both nodes (verbatim KD math) ----
#pragma unroll
  for (int it = 0; it < 2; ++it) {
    const int ln = ni + 8 * it;
    const float h0 = (it == 0) ? h0A : h0B;
    const float h1a = (it == 0) ? h1A[0] : h1B[0];
    const float h1b = (it == 0) ? h1A[1] : h1B[1];
    const float h1c = (it == 0) ? h1A[2] : h1B[2];
    float h2v[5];
#pragma unroll
    for (int j = 0; j < 5; ++j) h2v[j] = (it == 0) ? h2A[j] : h2B[j];

    const float* Vp = &Vt[ln][u];
    const float v0 = Vp[0], v15 = Vp[32], v2 = Vp[64], v3 = Vp[96];
    const float v5 = Vp[128], v6 = Vp[160];

    const float d11 = h1a * h1a + h1b * h1b + h1c * h1c;
    const float d22 = h2v[0] * h2v[0] + h2v[1] * h2v[1] + h2v[2] * h2v[2] +
                      h2v[3] * h2v[3] + h2v[4] * h2v[4];
    float y0 = v0 * h0 * h0 + v2 * d11 * ISQRT3 + v5 * d22 * ISQRT5;

    const float o00 = h1a * h1a, o01 = h1a * h1b, o02 = h1a * h1c;
    const float o11 = h1b * h1b, o12 = h1b * h1c, o22 = h1c * h1c;
    const float t40 = TWOS2f * o01, t41 = TWOS2f * o12;
    const float t42 = S6f * (2.f * o22 - o00 - o11);
    const float t43 = TWOS2f * o02, t44 = S2f * (o00 - o11);

    const float A00 = -S6f * h2v[2] + S2f * h2v[4];
    const float A01 = S2f * h2v[0];
    const float A02 = S2f * h2v[3];
    const float A11 = -S6f * h2v[2] - S2f * h2v[4];
    const float A12 = S2f * h2v[1];
    const float A22 = TWOS6f * h2v[2];
    const float B00 = A00 * A00 + A01 * A01 + A02 * A02;
    const float B01 = A00 * A01 + A01 * A11 + A02 * A12;
    const float B02 = A00 * A02 + A01 * A12 + A02 * A22;
    const float B11 = A01 * A01 + A11 * A11 + A12 * A12;
    const float B12 = A01 * A02 + A11 * A12 + A12 * A22;
    const float B22 = A02 * A02 + A12 * A12 + A22 * A22;
    const float t80 = TWOS2f * B01, t81 = TWOS2f * B12;
    const float t82 = S6f * (2.f * B22 - B00 - B11);
    const float t83 = TWOS2f * B02, t84 = S2f * (B00 - B11);

    const float w15 = v15 * h0;
    const float v6n = v6 * norm2;
    float y2r[5];
    y2r[0] = w15 * h2v[0] + v3 * t40 + v6n * t80;
    y2r[1] = w15 * h2v[1] + v3 * t41 + v6n * t81;
    y2r[2] = w15 * h2v[2] + v3 * t42 + v6n * t82;
    y2r[3] = w15 * h2v[3] + v3 * t43 + v6n * t83;
    y2r[4] = w15 * h2v[4] + v3 * t44 + v6n * t84;

#pragma unroll
    for (int off = 16; off > 0; off >>= 1) {
      y0 += __shfl_xor(y0, off, 32);
#pragma unroll
      for (int r = 0; r < 5; ++r) y2r[r] += __shfl_xor(y2r[r], off, 32);
    }

    if (u == 0) {
      sphs[ln][0] = y0;
#pragma unroll
      for (int r = 0; r < 5; ++r) sphs[ln][1 + r] = y2r[r];
    }
  }
  __syncthreads();

  // ---- phase E: Q-contract + segment atomics over the 16-node tile ----
  if (tid < 9) {
    const float QW[9][6] = {
        {ISQRT3, 0.f, 0.f, -S6f, 0.f, S2f},
        {0.f, S2f, 0.f, 0.f, 0.f, 0.f},
        {0.f, 0.f, 0.f, 0.f, S2f, 0.f},
        {0.f, S2f, 0.f, 0.f, 0.f, 0.f},
        {ISQRT3, 0.f, 0.f, -S6f, 0.f, -S2f},
        {0.f, 0.f, S2f, 0.f, 0.f, 0.f},
        {0.f, 0.f, 0.f, 0.f, S2f, 0.f},
        {0.f, 0.f, S2f, 0.f, 0.f, 0.f},
        {ISQRT3, 0.f, 0.f, TWOS6f, 0.f, 0.f}};
    const int a = tid / 3, b = tid % 3;
    const int rolled = ((a + 1) % 3) * 3 + ((b + 1) % 3);
    const float c0 = QW[tid][0], c1 = QW[tid][1], c2 = QW[tid][2];
    const float c3 = QW[tid][3], c4 = QW[tid][4], c5 = QW[tid][5];
    int cur_g = batch[n0];
    float acc = 0.f;
#pragma unroll
    for (int q = 0; q < 16; ++q) {
      const int g = batch[n0 + q];
      const float val = c0 * sphs[q][0] + c1 * sphs[q][1] + c2 * sphs[q][2] +
                        c3 * sphs[q][3] + c4 * sphs[q][4] + c5 * sphs[q][5];
      if (g != cur_g) {
        atomicAdd(out + cur_g * 9 + rolled, acc);
        acc = 0.f;
        cur_g = g;
      }
      acc += val;
    }
    atomicAdd(out + cur_g * 9 + rolled, acc);
  }
}

extern "C" void kernel_launch(void* const* d_in, const int* in_sizes, int n_in,
                              void* d_out, int out_size, void* d_ws, size_t ws_size,
                              hipStream_t stream) {
  const float* x_scalar = (const float*)d_in[0];
  const float* x_sph    = (const float*)d_in[1];
  const int*   batch    = (const int*)d_in[2];
  const float* W0e      = (const float*)d_in[3];
  const float* W1o      = (const float*)d_in[4];
  const float* W2e      = (const float*)d_in[5];
  const float* Wm1      = (const float*)d_in[6];
  const float* bm1      = (const float*)d_in[7];
  const float* Wm2      = (const float*)d_in[8];
  const float* bm2      = (const float*)d_in[9];
  const float* P0       = (const float*)d_in[10];
  // P1 (d_in[11]) provably unused: C111/C221 antisymmetric vs h(x)h of same h.
  const float* P2       = (const float*)d_in[12];
  float* ws  = (float*)d_ws;
  float* out = (float*)d_out;

  if (ws_size < (size_t)WS_FLOATS * sizeof(float)) return;

  // host-side C222 normalization (pure CPU double math; = sqrt(12/7))
  double Q2[5][3][3] = {};
  const double s2d = 0.70710678118654752440, s6d = 0.40824829046386301637;
  Q2[0][0][1] = Q2[0][1][0] = s2d;
  Q2[1][1][2] = Q2[1][2][1] = s2d;
  Q2[2][0][0] = Q2[2][1][1] = -s6d; Q2[2][2][2] = 2.0 * s6d;
  Q2[3][0][2] = Q2[3][2][0] = s2d;
  Q2[4][0][0] = s2d; Q2[4][1][1] = -s2d;
  double ss = 0.0;
  for (int i = 0; i < 5; ++i)
    for (int jj = 0; jj < 5; ++jj) {
      double S[3][3];
      for (int a = 0; a < 3; ++a)
        for (int d = 0; d < 3; ++d) {
          double m1 = 0, m2 = 0;
          for (int b = 0; b < 3; ++b) {
            m1 += Q2[i][a][b] * Q2[jj][d][b];
            m2 += Q2[i][d][b] * Q2[jj][a][b];
          }
          S[a][d] = 0.5 * (m1 + m2);
        }
      double tr = (S[0][0] + S[1][1] + S[2][2]) / 3.0;
      S[0][0] -= tr; S[1][1] -= tr; S[2][2] -= tr;
      for (int kk = 0; kk < 5; ++kk) {
        double cc = 0;
        for (int a = 0; a < 3; ++a)
          for (int d = 0; d < 3; ++d) cc += Q2[kk][a][d] * S[a][d];
        ss += cc * cc;
      }
    }
  const float norm2 = (float)sqrt(5.0 / ss);

  prep_kernel<<<49, 256, 0, stream>>>(Wm2, bm2, P0, P2, ws, out);
  fused_kernel<<<1250, 256, 0, stream>>>(x_scalar, x_sph, W0e, W1o, W2e,
                                         Wm1, bm1, ws, batch, out, norm2);
}